// Round 6
// baseline (109.923 us; speedup 1.0000x reference)
//
#include <hip/hip_runtime.h>

// N = 4096 bodies, 2D. Broad phase keeps first 4N row-major AABB hits,
// exact phase keeps first N true penetrations, resolve is last-write-wins.
#define NB 4096
#define KBROAD (4 * NB)   // 16384
#define KEXACT NB         // 4096
typedef unsigned long long u64;

// ---------------------------------------------------------------------------
// K1: fused broad phase (count + fill) via single-pass decoupled lookback.
// 512 blocks x 256 threads; wave wv owns rows b*8 + wv*2 + {0,1}. AABB masks
// stay in registers (lane c holds chunk c's 64-bit mask). Block publishes its
// 8-row aggregate with a flag bit; wave 0 spin-sums all predecessor
// aggregates (parallel lookback, agent-scope acquire). Then fill: per-lane
// bit-walk with the inline exact circle test; penetrating slots get
// penvec[rank] + packed pij[rank] (valid-encodable: top nibbles zero).
// Non-penetrating slots stay 0xAA-poisoned - that IS the miss flag.
// Also inits last_i/last_j (consumed 2 dispatches later).
// ---------------------------------------------------------------------------
__global__ __launch_bounds__(256) void broad_kernel(
    const float2* __restrict__ pos, const float* __restrict__ rad,
    float2* __restrict__ penvec, unsigned* __restrict__ pij,
    int* __restrict__ agg, int* __restrict__ totalp,
    int* __restrict__ last_i, int* __restrict__ last_j) {
  __shared__ int rowcnt[8];
  __shared__ int sbase;
  int t = threadIdx.x, b = blockIdx.x;
  int wv = t >> 6, lane = t & 63;
  int gid = b * 256 + t;
  if (gid < NB) { last_i[gid] = -1; last_j[gid] = -1; }

  // ---- phase A: AABB tests for my 2 rows, masks in registers.
  int r0 = b * 8 + wv * 2;
  float2 p0 = pos[r0], p1 = pos[r0 + 1];
  float ra0 = rad[r0], ra1 = rad[r0 + 1];
  u64 mw0 = 0, mw1 = 0;       // lane c keeps the mask word of chunk c
  int c0 = 0, c1 = 0;
  for (int c = 0; c < 64; ++c) {
    int j = c * 64 + lane;
    float2 pj = pos[j];
    float rj = rad[j];
    float rs0 = ra0 + rj, rs1 = ra1 + rj;
    bool h0 = (j != r0) && (fabsf(p0.x - pj.x) <= rs0) && (fabsf(p0.y - pj.y) <= rs0);
    bool h1 = (j != r0 + 1) && (fabsf(p1.x - pj.x) <= rs1) && (fabsf(p1.y - pj.y) <= rs1);
    u64 m0 = __ballot(h0);
    u64 m1 = __ballot(h1);
    if (lane == c) { mw0 = m0; mw1 = m1; }
    c0 += __popcll(m0);
    c1 += __popcll(m1);
  }
  if (lane == 0) { rowcnt[wv * 2] = c0; rowcnt[wv * 2 + 1] = c1; }
  __syncthreads();

  // ---- publish aggregate (flag bit 0x40000000; poison 0xAAAAAAAA fails the
  // (v & 0xC0000000) == 0x40000000 check).
  if (t == 0) {
    int s = 0;
    #pragma unroll
    for (int k = 0; k < 8; ++k) s += rowcnt[k];
    __hip_atomic_store(&agg[b], 0x40000000 | s, __ATOMIC_RELEASE,
                       __HIP_MEMORY_SCOPE_AGENT);
  }
  // ---- lookback: wave 0 sums predecessors (parallel spin, no chain).
  if (wv == 0) {
    int sum = 0;
    for (int base = 0; base < b; base += 64) {
      int idx = base + lane;
      int v = 0;
      if (idx < b) {
        do {
          v = __hip_atomic_load(&agg[idx], __ATOMIC_ACQUIRE,
                                __HIP_MEMORY_SCOPE_AGENT);
        } while ((v & 0xC0000000) != 0x40000000);
        v &= 0x3FFFFFFF;
      }
      sum += v;
    }
    #pragma unroll
    for (int off = 32; off; off >>= 1) sum += __shfl_down(sum, off);
    if (lane == 0) sbase = sum;
  }
  __syncthreads();
  int bbase = sbase;
  if (b == 511 && t == 0) {
    int s = 0;
    #pragma unroll
    for (int k = 0; k < 8; ++k) s += rowcnt[k];
    totalp[0] = bbase + s;    // uncapped; exact kernel clamps to KBROAD
  }

  // ---- fill my 2 rows from the register masks.
  int rb0 = bbase;
  for (int k = 0; k < wv * 2; ++k) rb0 += rowcnt[k];
  int rb1 = rb0 + rowcnt[wv * 2];
  #pragma unroll
  for (int q = 0; q < 2; ++q) {
    int r = r0 + q;
    int rowbase = q ? rb1 : rb0;         // uniform across wave
    u64 myw = q ? mw1 : mw0;
    if (rowbase >= KBROAD) continue;     // uniform branch
    int cnt = __popcll(myw);
    int v2 = cnt;
    #pragma unroll
    for (int off = 1; off < 64; off <<= 1) {
      int u = __shfl_up(v2, off);
      if (lane >= off) v2 += u;
    }
    int rank = rowbase + v2 - cnt;       // base rank of my chunk
    if (!myw) continue;                  // per-lane; no wave ops below
    float2 pr = pos[r];
    float rr = rad[r];
    u64 m = myw;
    while (m && rank < KBROAD) {
      int bit = __builtin_ctzll(m);
      m &= m - 1;
      int j = (lane << 6) + bit;
      // exact circle test, rn ops to bit-match numpy (no FMA contraction)
      float2 pj = pos[j];
      float dx = pr.x - pj.x, dy = pr.y - pj.y;
      float ss = __fadd_rn(__fadd_rn(__fmul_rn(dx, dx), __fmul_rn(dy, dy)), 1e-12f);
      float dist = __fsqrt_rn(ss);
      float pen = __fsub_rn(__fadd_rn(rr, rad[j]), dist);
      if (pen > 0.0f) {
        float sc = __fdiv_rn(pen, dist);
        penvec[rank] = make_float2(__fmul_rn(dx, sc), __fmul_rn(dy, sc));
        pij[rank] = ((unsigned)r << 16) | (unsigned)j;   // top nibbles 0
      }
      ++rank;
    }
  }
}

// ---------------------------------------------------------------------------
// K2: exact compaction. Hit flag for slot s = (pij[s] valid) && (s < total);
// 0xAA poison can never look valid. Each block redundantly builds the 16384-
// bit hit mask (thread t owns slots t*64..+63), block-scans it, then places
// its 256-slot window (1 slot/thread): ev[rank] + global last-writer
// atomicMax. Grid: 64 blocks x 256 threads.
// ---------------------------------------------------------------------------
__global__ __launch_bounds__(256) void exact_kernel(
    const unsigned* __restrict__ pij, const float2* __restrict__ penvec,
    const int* __restrict__ totalp, float2* __restrict__ ev,
    int* __restrict__ last_i, int* __restrict__ last_j) {
  __shared__ u64 bm[256];
  __shared__ int eb[256];
  __shared__ int wsum[4];
  int t = threadIdx.x;
  int wv = t >> 6, lane = t & 63;
  int total = totalp[0];
  if (total > KBROAD) total = KBROAD;
  u64 m = 0;
  int base = t * 64;
  #pragma unroll
  for (int k = 0; k < 16; ++k) {
    uint4 d = ((const uint4*)pij)[t * 16 + k];
    int s = base + 4 * k;
    unsigned n = 0;
    n |= (((d.x & 0xF000F000u) == 0u) && (s + 0 < total)) ? 1u : 0u;
    n |= (((d.y & 0xF000F000u) == 0u) && (s + 1 < total)) ? 2u : 0u;
    n |= (((d.z & 0xF000F000u) == 0u) && (s + 2 < total)) ? 4u : 0u;
    n |= (((d.w & 0xF000F000u) == 0u) && (s + 3 < total)) ? 8u : 0u;
    m |= (u64)n << (4 * k);
  }
  int cnt = __popcll(m);
  int v = cnt;
  #pragma unroll
  for (int off = 1; off < 64; off <<= 1) {
    int u = __shfl_up(v, off);
    if (lane >= off) v += u;
  }
  if (lane == 63) wsum[wv] = v;
  bm[t] = m;
  __syncthreads();
  int wbase = 0;
  #pragma unroll
  for (int w = 0; w < 4; ++w) if (w < wv) wbase += wsum[w];
  eb[t] = wbase + v - cnt;   // exclusive base of chunk t
  __syncthreads();
  int s = blockIdx.x * 256 + t;
  u64 w = bm[s >> 6];
  if ((w >> (s & 63)) & 1ull) {
    int rank = eb[s >> 6] + __popcll(w & (((u64)1 << (s & 63)) - 1ull));
    if (rank < KEXACT) {
      ev[rank] = penvec[s];
      unsigned p = pij[s];
      atomicMax(&last_i[p >> 16], rank);
      atomicMax(&last_j[p & 0xFFFFu], rank);
    }
  }
}

// ---------------------------------------------------------------------------
// K3: resolve. j-scatter wins over i-scatter; both read ORIGINAL pos.
// Grid: 16 blocks x 256 threads.
// ---------------------------------------------------------------------------
__global__ __launch_bounds__(256) void combine_kernel(
    const float2* __restrict__ pos, const int* __restrict__ last_i,
    const int* __restrict__ last_j, const float2* __restrict__ ev,
    float2* __restrict__ out) {
  int b = blockIdx.x * blockDim.x + threadIdx.x;
  float2 p = pos[b];
  int lj = last_j[b], li = last_i[b];
  float2 o = p;
  if (lj >= 0) {
    o.x = __fsub_rn(p.x, __fmul_rn(0.5f, ev[lj].x));
    o.y = __fsub_rn(p.y, __fmul_rn(0.5f, ev[lj].y));
  } else if (li >= 0) {
    o.x = __fadd_rn(p.x, __fmul_rn(0.5f, ev[li].x));
    o.y = __fadd_rn(p.y, __fmul_rn(0.5f, ev[li].y));
  }
  out[b] = o;
}

// ---------------------------------------------------------------------------
extern "C" void kernel_launch(void* const* d_in, const int* in_sizes, int n_in,
                              void* d_out, int out_size, void* d_ws, size_t ws_size,
                              hipStream_t stream) {
  const float2* pos = (const float2*)d_in[0];
  const float* rad = (const float*)d_in[1];
  float2* out = (float2*)d_out;

  // Workspace layout (~260 KB).
  float2* penvec = (float2*)d_ws;                 // KBROAD float2 (128 KB)
  float2* ev = penvec + KBROAD;                   // KEXACT float2 (32 KB)
  unsigned* pij = (unsigned*)(ev + KEXACT);       // KBROAD u32 (64 KB)
  int* agg = (int*)(pij + KBROAD);                // 512
  int* totalp = agg + 512;                        // 1
  int* last_i = totalp + 1;                       // NB
  int* last_j = last_i + NB;                      // NB

  broad_kernel<<<512, 256, 0, stream>>>(pos, rad, penvec, pij, agg, totalp,
                                        last_i, last_j);
  exact_kernel<<<64, 256, 0, stream>>>(pij, penvec, totalp, ev, last_i,
                                       last_j);
  combine_kernel<<<16, 256, 0, stream>>>(pos, last_i, last_j, ev, out);
}

// Round 7
// 93.274 us; speedup vs baseline: 1.1785x; 1.1785x over previous
//
#include <hip/hip_runtime.h>

// N = 4096 bodies, 2D. Broad phase keeps first 4N row-major AABB hits,
// exact phase keeps first N true penetrations, resolve is last-write-wins.
#define NB 4096
#define KBROAD (4 * NB)   // 16384
#define KEXACT NB         // 4096
typedef unsigned long long u64;

// ---------------------------------------------------------------------------
// K1: broad-phase counts + per-row hit bitmasks. 2 rows per wave.
// Also inits last_key = -1 (consumed by K3/K4; ws is 0xAA-poisoned).
// Grid: 512 blocks x 256 threads = 2048 waves.
// ---------------------------------------------------------------------------
__global__ __launch_bounds__(256) void count_kernel(
    const float2* __restrict__ pos, const float* __restrict__ rad,
    int* __restrict__ row_counts, u64* __restrict__ masks,
    int* __restrict__ last_key) {
  int gid = blockIdx.x * blockDim.x + threadIdx.x;
  if (gid < NB) last_key[gid] = -1;
  int wave = gid >> 6;
  int lane = gid & 63;
  int r0 = wave * 2;          // rows r0, r0+1
  float2 p0 = pos[r0], p1 = pos[r0 + 1];
  float ra0 = rad[r0], ra1 = rad[r0 + 1];
  u64 mw0 = 0, mw1 = 0;       // lane c keeps the mask word of chunk c
  int c0 = 0, c1 = 0;
  for (int c = 0; c < 64; ++c) {
    int j = c * 64 + lane;
    float2 pj = pos[j];
    float rj = rad[j];
    float rs0 = ra0 + rj, rs1 = ra1 + rj;
    bool h0 = (j != r0) && (fabsf(p0.x - pj.x) <= rs0) && (fabsf(p0.y - pj.y) <= rs0);
    bool h1 = (j != r0 + 1) && (fabsf(p1.x - pj.x) <= rs1) && (fabsf(p1.y - pj.y) <= rs1);
    u64 m0 = __ballot(h0);
    u64 m1 = __ballot(h1);
    if (lane == c) { mw0 = m0; mw1 = m1; }
    c0 += __popcll(m0);
    c1 += __popcll(m1);
  }
  masks[(size_t)r0 * 64 + lane] = mw0;          // coalesced 512 B per row
  masks[(size_t)(r0 + 1) * 64 + lane] = mw1;
  if (lane == 0) { row_counts[r0] = c0; row_counts[r0 + 1] = c1; }
}

// ---------------------------------------------------------------------------
// K2: redundant per-block exclusive scan of row counts, then fill this
// block's 16 rows from stored masks (per-lane bit-walk) with the exact
// circle test inline. Penetrating slots get penvec[rank] + packed pij[rank]
// (top nibbles zero -> distinguishable from 0xAA poison = the miss flag).
// Block 0 thread 255 writes the grand total (its scan tail) to totalp.
// Grid: 256 blocks x 256 threads. rb is TRANSPOSED to avoid bank conflicts.
// ---------------------------------------------------------------------------
__global__ __launch_bounds__(256) void fill_kernel(
    const float2* __restrict__ pos, const float* __restrict__ rad,
    const int* __restrict__ row_counts, const u64* __restrict__ masks,
    float2* __restrict__ penvec, unsigned* __restrict__ pij,
    int* __restrict__ totalp) {
  __shared__ int rb[NB];     // transposed row-base table (16 KB)
  __shared__ int wsum[4];
  int t = threadIdx.x;
  int wv = t >> 6, lane = t & 63;
  // ---- stage 1: exclusive scan of 4096 counts (redundant per block).
  int c[16], s = 0;
  #pragma unroll
  for (int k = 0; k < 16; ++k) { c[k] = row_counts[t * 16 + k]; s += c[k]; }
  int v = s;  // wave inclusive scan
  #pragma unroll
  for (int off = 1; off < 64; off <<= 1) {
    int u = __shfl_up(v, off);
    if (lane >= off) v += u;
  }
  if (lane == 63) wsum[wv] = v;
  __syncthreads();
  int wbase = 0;
  #pragma unroll
  for (int w = 0; w < 4; ++w) if (w < wv) wbase += wsum[w];
  int run = wbase + v - s;   // exclusive base of thread t's first row
  #pragma unroll
  for (int k = 0; k < 16; ++k) { rb[k * 256 + t] = run; run += c[k]; }
  if (blockIdx.x == 0 && t == 255) totalp[0] = run;   // grand total (uncapped)
  __syncthreads();
  // ---- stage 2: fill 4 rows per wave, lane c owns chunk c of the row.
  for (int q = 0; q < 4; ++q) {
    int r = blockIdx.x * 16 + wv * 4 + q;
    int rowbase = rb[(r & 15) * 256 + (r >> 4)];   // uniform across wave
    if (rowbase >= KBROAD) continue;               // uniform branch
    u64 myw = masks[(size_t)r * 64 + lane];
    int cnt = __popcll(myw);
    int v2 = cnt;
    #pragma unroll
    for (int off = 1; off < 64; off <<= 1) {
      int u = __shfl_up(v2, off);
      if (lane >= off) v2 += u;
    }
    int rank = rowbase + v2 - cnt;                 // base rank of my chunk
    if (!myw) continue;                            // per-lane; no wave ops below
    float2 pr = pos[r];
    float rr = rad[r];
    u64 m = myw;
    while (m && rank < KBROAD) {
      int b = __builtin_ctzll(m);
      m &= m - 1;
      int j = (lane << 6) + b;
      // exact circle test, rn ops to bit-match numpy (no FMA contraction)
      float2 pj = pos[j];
      float dx = pr.x - pj.x, dy = pr.y - pj.y;
      float ss = __fadd_rn(__fadd_rn(__fmul_rn(dx, dx), __fmul_rn(dy, dy)), 1e-12f);
      float dist = __fsqrt_rn(ss);
      float pen = __fsub_rn(__fadd_rn(rr, rad[j]), dist);
      if (pen > 0.0f) {
        float sc = __fdiv_rn(pen, dist);
        penvec[rank] = make_float2(__fmul_rn(dx, sc), __fmul_rn(dy, sc));
        pij[rank] = ((unsigned)r << 16) | (unsigned)j;   // top nibbles 0
      }
      ++rank;
    }
  }
}

// ---------------------------------------------------------------------------
// K3: exact compaction. Hit flag for slot s = (pij[s] valid) && (s < total);
// 0xAA poison can never look valid. Each block redundantly builds the 16384-
// bit hit mask (thread t owns slots t*64..+63), block-scans it, then places
// its 256-slot window (1 slot/thread): ev[rank] + last-writer key atomicMax
// (key = isJ<<16 | rank: j-writes beat i-writes, higher rank wins in-class).
// Grid: 64 blocks x 256 threads.
// ---------------------------------------------------------------------------
__global__ __launch_bounds__(256) void exact_kernel(
    const unsigned* __restrict__ pij, const float2* __restrict__ penvec,
    const int* __restrict__ totalp, float2* __restrict__ ev,
    int* __restrict__ last_key) {
  __shared__ u64 bm[256];
  __shared__ int eb[256];
  __shared__ int wsum[4];
  int t = threadIdx.x;
  int wv = t >> 6, lane = t & 63;
  int total = totalp[0];
  if (total > KBROAD) total = KBROAD;
  u64 m = 0;
  int base = t * 64;
  #pragma unroll
  for (int k = 0; k < 16; ++k) {
    uint4 d = ((const uint4*)pij)[t * 16 + k];
    int s = base + 4 * k;
    unsigned n = 0;
    n |= (((d.x & 0xF000F000u) == 0u) && (s + 0 < total)) ? 1u : 0u;
    n |= (((d.y & 0xF000F000u) == 0u) && (s + 1 < total)) ? 2u : 0u;
    n |= (((d.z & 0xF000F000u) == 0u) && (s + 2 < total)) ? 4u : 0u;
    n |= (((d.w & 0xF000F000u) == 0u) && (s + 3 < total)) ? 8u : 0u;
    m |= (u64)n << (4 * k);
  }
  int cnt = __popcll(m);
  int v = cnt;
  #pragma unroll
  for (int off = 1; off < 64; off <<= 1) {
    int u = __shfl_up(v, off);
    if (lane >= off) v += u;
  }
  if (lane == 63) wsum[wv] = v;
  bm[t] = m;
  __syncthreads();
  int wbase = 0;
  #pragma unroll
  for (int w = 0; w < 4; ++w) if (w < wv) wbase += wsum[w];
  eb[t] = wbase + v - cnt;   // exclusive base of chunk t
  __syncthreads();
  int s = blockIdx.x * 256 + t;
  u64 w = bm[s >> 6];
  if ((w >> (s & 63)) & 1ull) {
    int rank = eb[s >> 6] + __popcll(w & (((u64)1 << (s & 63)) - 1ull));
    if (rank < KEXACT) {
      ev[rank] = penvec[s];
      unsigned p = pij[s];
      atomicMax(&last_key[p >> 16], rank);                 // i-side: key=rank
      atomicMax(&last_key[p & 0xFFFFu], 0x10000 | rank);   // j-side wins
    }
  }
}

// ---------------------------------------------------------------------------
// K4: resolve. key<0 -> untouched; bit16 -> j-side (minus), else i-side.
// Grid: 16 blocks x 256 threads.
// ---------------------------------------------------------------------------
__global__ __launch_bounds__(256) void combine_kernel(
    const float2* __restrict__ pos, const int* __restrict__ last_key,
    const float2* __restrict__ ev, float2* __restrict__ out) {
  int b = blockIdx.x * blockDim.x + threadIdx.x;
  float2 p = pos[b];
  int k = last_key[b];
  float2 o = p;
  if (k >= 0) {
    int rank = k & 0xFFFF;
    float2 e = ev[rank];
    if (k & 0x10000) {
      o.x = __fsub_rn(p.x, __fmul_rn(0.5f, e.x));
      o.y = __fsub_rn(p.y, __fmul_rn(0.5f, e.y));
    } else {
      o.x = __fadd_rn(p.x, __fmul_rn(0.5f, e.x));
      o.y = __fadd_rn(p.y, __fmul_rn(0.5f, e.y));
    }
  }
  out[b] = o;
}

// ---------------------------------------------------------------------------
extern "C" void kernel_launch(void* const* d_in, const int* in_sizes, int n_in,
                              void* d_out, int out_size, void* d_ws, size_t ws_size,
                              hipStream_t stream) {
  const float2* pos = (const float2*)d_in[0];
  const float* rad = (const float*)d_in[1];
  float2* out = (float2*)d_out;

  // Workspace layout (~2.25 MB). pij first for 16B alignment (uint4 reads).
  unsigned* pij = (unsigned*)d_ws;                // KBROAD u32 (64 KB)
  float2* penvec = (float2*)(pij + KBROAD);       // KBROAD float2 (128 KB)
  float2* ev = penvec + KBROAD;                   // KEXACT float2 (32 KB)
  u64* masks = (u64*)(ev + KEXACT);               // NB*64 u64 = 2 MB
  int* row_counts = (int*)(masks + (size_t)NB * 64);  // NB
  int* totalp = row_counts + NB;                  // 1
  int* last_key = totalp + 1;                     // NB

  count_kernel<<<512, 256, 0, stream>>>(pos, rad, row_counts, masks, last_key);
  fill_kernel<<<256, 256, 0, stream>>>(pos, rad, row_counts, masks, penvec,
                                       pij, totalp);
  exact_kernel<<<64, 256, 0, stream>>>(pij, penvec, totalp, ev, last_key);
  combine_kernel<<<16, 256, 0, stream>>>(pos, last_key, ev, out);
}